// Round 5
// baseline (277.112 us; speedup 1.0000x reference)
//
#include <hip/hip_runtime.h>

#define FEAT 128
#define LAT  16
#define NB   256        // buckets = dst >> 8
#define NPB  256        // nodes per bucket
#define PAD  16         // ints between global counters (64B line each)
#define S1   4          // blocks per bucket, conv1
#define S2   4          // blocks per bucket, conv2
// edge packing: v = (src << 16) | dst   (n = 65536 -> both fit 16 bits)
// bucket = (v >> 8) & 255, local node = v & 255, src = (unsigned)v >> 16

// ---------- P1: bucket histogram over dst ----------
__global__ void k_bhist(const int* __restrict__ dst, int E, int* __restrict__ bcnt) {
    __shared__ int h[NB];
    int t = threadIdx.x;
    h[t] = 0;
    __syncthreads();
    int per = ((E + gridDim.x - 1) / gridDim.x + 3) & ~3;
    int e0 = blockIdx.x * per;
    int e1 = min(e0 + per, E);
    if (e0 < e1) {
        const int4* d4 = (const int4*)(dst + e0);
        int nq = (e1 - e0) >> 2;
        for (int q = t; q < nq; q += blockDim.x) {
            int4 v = d4[q];
            atomicAdd(&h[((unsigned)v.x) >> 8], 1);
            atomicAdd(&h[((unsigned)v.y) >> 8], 1);
            atomicAdd(&h[((unsigned)v.z) >> 8], 1);
            atomicAdd(&h[((unsigned)v.w) >> 8], 1);
        }
        for (int e = e0 + (nq << 2) + t; e < e1; e += blockDim.x)
            atomicAdd(&h[((unsigned)dst[e]) >> 8], 1);
    }
    __syncthreads();
    if (h[t]) atomicAdd(&bcnt[t * PAD], h[t]);
}

// ---------- tiny scan of 256 bucket counts ----------
__global__ void k_bscan(const int* __restrict__ bcnt, int* __restrict__ boff,
                        int* __restrict__ bcur) {
    __shared__ int s[NB];
    int t = threadIdx.x;
    s[t] = bcnt[t * PAD];
    __syncthreads();
    for (int off = 1; off < NB; off <<= 1) {
        int v = (t >= off) ? s[t - off] : 0;
        __syncthreads();
        s[t] += v;
        __syncthreads();
    }
    int excl = (t == 0) ? 0 : s[t - 1];
    boff[t] = excl;
    bcur[t * PAD] = excl;
    if (t == NB - 1) boff[NB] = s[t];
}

// ---------- P2: single-pass partition via LDS staging ----------
__global__ void k_part(const int* __restrict__ src, const int* __restrict__ dst, int E,
                       int* __restrict__ bcur, int* __restrict__ ebuf) {
    __shared__ int4 stage4[512];            // 2048 packed edges, 8 KB
    __shared__ int h[NB];
    __shared__ int lcur[NB];
    int* stage = (int*)stage4;
    int t = threadIdx.x;
    h[t] = 0;
    __syncthreads();
    int per = ((E + gridDim.x - 1) / gridDim.x + 3) & ~3;   // 2048 @ grid 1024
    int e0 = blockIdx.x * per;
    int e1 = min(e0 + per, E);
    int cnt = max(e1 - e0, 0);
    if (cnt > 0) {
        const int4* d4 = (const int4*)(dst + e0);
        const int4* s4 = (const int4*)(src + e0);
        int nq = cnt >> 2;
        for (int q = t; q < nq; q += 256) {
            int4 dv = d4[q];
            int4 sv = s4[q];
            atomicAdd(&h[((unsigned)dv.x) >> 8], 1);
            atomicAdd(&h[((unsigned)dv.y) >> 8], 1);
            atomicAdd(&h[((unsigned)dv.z) >> 8], 1);
            atomicAdd(&h[((unsigned)dv.w) >> 8], 1);
            stage4[q] = make_int4((sv.x << 16) | dv.x, (sv.y << 16) | dv.y,
                                  (sv.z << 16) | dv.z, (sv.w << 16) | dv.w);
        }
        for (int e = (nq << 2) + t; e < cnt; e += 256) {
            int d = dst[e0 + e], s = src[e0 + e];
            atomicAdd(&h[((unsigned)d) >> 8], 1);
            stage[e] = (s << 16) | d;
        }
    }
    __syncthreads();
    if (h[t]) lcur[t] = atomicAdd(&bcur[t * PAD], h[t]);
    __syncthreads();
    for (int e = t; e < cnt; e += 256) {
        int v = stage[e];
        int b = (v >> 8) & 255;                 // bucket = dst >> 8
        int pos = atomicAdd(&lcur[b], 1);
        ebuf[pos] = v;
    }
}

// ---------- per-node degree (split buckets, global int merge) ----------
__global__ void k_degS(const int* __restrict__ ebuf, const int* __restrict__ boff,
                       int* __restrict__ dcnt) {
    __shared__ int h[NPB];
    int t = threadIdx.x;
    int b = blockIdx.x >> 2, s = blockIdx.x & 3;
    h[t] = 0;
    __syncthreads();
    int e0 = boff[b], e1 = boff[b + 1];
    int len = e1 - e0, qs = (len + S2 - 1) >> 2;
    int st = e0 + s * qs, en = min(st + qs, e1);
    for (int e = st + t; e < en; e += 256) atomicAdd(&h[ebuf[e] & 255], 1);
    __syncthreads();
    if (h[t]) atomicAdd(&dcnt[b * NPB + t], h[t]);
}

// ---------- hs[i][:] = dinv[i] * (x[i] @ W1) ----------
__global__ void k_hs(const float* __restrict__ x, const float* __restrict__ W1,
                     const int* __restrict__ dcnt, float* __restrict__ hs, int n) {
    __shared__ float w[FEAT * LAT];
    int t = threadIdx.x;
    for (int i = t; i < FEAT * LAT; i += blockDim.x) w[i] = W1[i];
    __syncthreads();
    int node = blockIdx.x * blockDim.x + t;
    if (node >= n) return;
    float acc[LAT];
#pragma unroll
    for (int j = 0; j < LAT; ++j) acc[j] = 0.f;
    const float4* xr = (const float4*)(x + (size_t)node * FEAT);
#pragma unroll 4
    for (int k4 = 0; k4 < FEAT / 4; ++k4) {
        float4 xv = xr[k4];
#pragma unroll
        for (int j = 0; j < LAT; ++j) {
            acc[j] += xv.x * w[(4 * k4 + 0) * LAT + j]
                    + xv.y * w[(4 * k4 + 1) * LAT + j]
                    + xv.z * w[(4 * k4 + 2) * LAT + j]
                    + xv.w * w[(4 * k4 + 3) * LAT + j];
        }
    }
    float dv = rsqrtf((float)(dcnt[node] + 1));
    float4* o = (float4*)(hs + (size_t)node * LAT);
#pragma unroll
    for (int q = 0; q < 4; ++q) {
        float4 v;
        v.x = acc[4 * q + 0] * dv; v.y = acc[4 * q + 1] * dv;
        v.z = acc[4 * q + 2] * dv; v.w = acc[4 * q + 3] * dv;
        o[q] = v;
    }
}

// ---------- conv1 edges: split buckets, LDS acc, global fp32 atomic merge ----------
__global__ __launch_bounds__(256) void k_conv1(const float* __restrict__ hs,
        const int* __restrict__ ebuf, const int* __restrict__ boff,
        float* __restrict__ hs2) {
    __shared__ float acc[NPB * LAT];      // 16 KB
    int t = threadIdx.x;
    int b = blockIdx.x >> 2, s = blockIdx.x & 3;
    float4* accv = (float4*)acc;
    for (int i = t; i < NPB * LAT / 4; i += 256) accv[i] = make_float4(0.f, 0.f, 0.f, 0.f);
    __syncthreads();
    int e0 = boff[b], e1 = boff[b + 1];
    int len = e1 - e0, qs = (len + S1 - 1) >> 2;
    int st = e0 + s * qs, en = min(st + qs, e1);
    int j = t & 15;
    int grp = t >> 4;                     // 16 edge groups
    int e = st + grp;
    for (; e + 48 < en; e += 64) {
        int v0 = ebuf[e], v1 = ebuf[e + 16], v2 = ebuf[e + 32], v3 = ebuf[e + 48];
        float a0 = hs[(size_t)((unsigned)v0 >> 16) * LAT + j];
        float a1 = hs[(size_t)((unsigned)v1 >> 16) * LAT + j];
        float a2 = hs[(size_t)((unsigned)v2 >> 16) * LAT + j];
        float a3 = hs[(size_t)((unsigned)v3 >> 16) * LAT + j];
        atomicAdd(&acc[(v0 & 255) * LAT + j], a0);
        atomicAdd(&acc[(v1 & 255) * LAT + j], a1);
        atomicAdd(&acc[(v2 & 255) * LAT + j], a2);
        atomicAdd(&acc[(v3 & 255) * LAT + j], a3);
    }
    for (; e < en; e += 16) {
        int v = ebuf[e];
        atomicAdd(&acc[(v & 255) * LAT + j], hs[(size_t)((unsigned)v >> 16) * LAT + j]);
    }
    __syncthreads();
    float* dstp = hs2 + (size_t)b * NPB * LAT;
    for (int i = t; i < NPB * LAT; i += 256)
        atomicAdd(&dstp[i], acc[i]);      // lane-coalesced, fire-and-forget
}

// ---------- fin1: h1 = relu(dinv*(hs2+hs)+b1); g = dinv*(h1 . W2) ----------
__global__ void k_fin1(const float* __restrict__ hs, const float* __restrict__ hs2,
                       const int* __restrict__ dcnt, const float* __restrict__ b1,
                       const float* __restrict__ W2, float* __restrict__ g) {
    int t = threadIdx.x;
    int j = t & 15;
    int node = blockIdx.x * 16 + (t >> 4);
    float dv = rsqrtf((float)(dcnt[node] + 1));
    size_t idx = (size_t)node * LAT + j;
    float h1 = fmaxf(dv * (hs2[idx] + hs[idx]) + b1[j], 0.f);
    float p = h1 * W2[j];
#pragma unroll
    for (int off = 8; off; off >>= 1) p += __shfl_xor(p, off, 16);
    if (j == 0) g[node] = dv * p;
}

// ---------- conv2 edges: split buckets, LDS acc, global merge ----------
__global__ void k_conv2(const float* __restrict__ g, const int* __restrict__ ebuf,
                        const int* __restrict__ boff, float* __restrict__ out2) {
    __shared__ float acc[NPB];
    int t = threadIdx.x;
    int b = blockIdx.x >> 2, s = blockIdx.x & 3;
    acc[t] = 0.f;
    __syncthreads();
    int e0 = boff[b], e1 = boff[b + 1];
    int len = e1 - e0, qs = (len + S2 - 1) >> 2;
    int st = e0 + s * qs, en = min(st + qs, e1);
    int e = st + t;
    for (; e + 768 < en; e += 1024) {
        int v0 = ebuf[e], v1 = ebuf[e + 256], v2 = ebuf[e + 512], v3 = ebuf[e + 768];
        float a0 = g[(unsigned)v0 >> 16], a1 = g[(unsigned)v1 >> 16];
        float a2 = g[(unsigned)v2 >> 16], a3 = g[(unsigned)v3 >> 16];
        atomicAdd(&acc[v0 & 255], a0);
        atomicAdd(&acc[v1 & 255], a1);
        atomicAdd(&acc[v2 & 255], a2);
        atomicAdd(&acc[v3 & 255], a3);
    }
    for (; e < en; e += 256) {
        int v = ebuf[e];
        atomicAdd(&acc[v & 255], g[(unsigned)v >> 16]);
    }
    __syncthreads();
    if (acc[t] != 0.f) atomicAdd(&out2[b * NPB + t], acc[t]);
}

// ---------- fin2: out = dinv*(out2 + g) + b2 ----------
__global__ void k_fin2(const float* __restrict__ out2, const float* __restrict__ g,
                       const int* __restrict__ dcnt, const float* __restrict__ b2,
                       float* __restrict__ out, int n) {
    int i = blockIdx.x * 256 + threadIdx.x;
    if (i < n) {
        float dv = rsqrtf((float)(dcnt[i] + 1));
        out[i] = dv * (out2[i] + g[i]) + b2[0];
    }
}

extern "C" void kernel_launch(void* const* d_in, const int* in_sizes, int n_in,
                              void* d_out, int out_size, void* d_ws, size_t ws_size,
                              hipStream_t stream) {
    const float* x  = (const float*)d_in[0];
    const float* W1 = (const float*)d_in[1];
    const float* b1 = (const float*)d_in[2];
    const float* W2 = (const float*)d_in[3];
    const float* b2 = (const float*)d_in[4];
    const int*   ei = (const int*)d_in[5];

    int n = in_sizes[0] / FEAT;      // 65536 nodes
    int E = in_sizes[5] / 2;         // 2097152 edges
    const int* srcp = ei;
    const int* dstp = ei + E;

    // workspace layout (4-byte elements); leading region is the memset block
    int*   bcnt = (int*)d_ws;                        // NB*PAD
    int*   dcnt = bcnt + NB * PAD;                   // n
    float* hs2  = (float*)(dcnt + n);                // n*LAT
    float* out2 = hs2 + (size_t)n * LAT;             // n
    // ---- end of zeroed region ----
    int*   bcur = (int*)(out2 + n);                  // NB*PAD
    int*   boff = bcur + NB * PAD;                   // NB+1 (pad 64)
    float* g    = (float*)(boff + NB + 64);          // n
    float* hs   = g + n;                             // n*LAT
    int*   ebuf = (int*)(hs + (size_t)n * LAT);      // E

    size_t zbytes = ((size_t)NB * PAD + n + (size_t)n * LAT + n) * sizeof(int);
    hipMemsetAsync(bcnt, 0, zbytes, stream);

    k_bhist<<<1024, NB, 0, stream>>>(dstp, E, bcnt);
    k_bscan<<<1, NB, 0, stream>>>(bcnt, boff, bcur);
    k_part <<<1024, NB, 0, stream>>>(srcp, dstp, E, bcur, ebuf);
    k_degS <<<NB * S2, NPB, 0, stream>>>(ebuf, boff, dcnt);
    k_hs   <<<(n + 255) / 256, 256, 0, stream>>>(x, W1, dcnt, hs, n);
    k_conv1<<<NB * S1, 256, 0, stream>>>(hs, ebuf, boff, hs2);
    k_fin1 <<<n / 16, 256, 0, stream>>>(hs, hs2, dcnt, b1, W2, g);
    k_conv2<<<NB * S2, NPB, 0, stream>>>(g, ebuf, boff, out2);
    k_fin2 <<<n / 256, 256, 0, stream>>>(out2, g, dcnt, b2, (float*)d_out, n);
}